// Round 5
// baseline (250.270 us; speedup 1.0000x reference)
//
#include <hip/hip_runtime.h>
#include <hip/hip_bf16.h>
#include <math.h>

#define NCELL 125000
#define KNBR  26
#define D     32
#define MC    64            // cells per moe block

#define SXE (127.0f/7.0f)   // X encode scale (clamp +-7)
#define SXD (7.0f/127.0f)   // X decode
#define SMD (1.0f/127.0f)   // M decode (tanh in [-1,1])

__device__ __forceinline__ float fast_tanh(float x) {
    float e = __expf(2.0f * x);
    return 1.0f - 2.0f / (e + 1.0f);
}
__device__ __forceinline__ float bf2f(unsigned int h) {
    return __uint_as_float(h << 16);
}

// ---- kernel 1: M = tanh(X @ Wm + bm) -> int8 ; Xq = int8(X) ----
// thread = (c,d); N*D = 4,000,000 = 256 * 15625 exactly
__global__ void __launch_bounds__(256) msg_kernel(
    const float* __restrict__ X, const float* __restrict__ Wm,
    const float* __restrict__ bm,
    signed char* __restrict__ Xq, signed char* __restrict__ Mq)
{
    __shared__ float sX[256];
    int t = blockIdx.x * 256 + threadIdx.x;
    float v = X[t];
    sX[threadIdx.x] = v;
    float xc = fminf(fmaxf(v, -7.f), 7.f);
    Xq[t] = (signed char)__float2int_rn(xc * SXE);
    __syncthreads();
    int d = t & 31;
    int base = threadIdx.x & ~31;
    float acc = bm[d];
#pragma unroll
    for (int j = 0; j < D; ++j)
        acc = fmaf(sX[base + j], Wm[j * D + d], acc);
    Mq[t] = (signed char)__float2int_rn(fast_tanh(acc) * 127.0f);
}

// ---- kernel 2: int8 gather + tier means -> aggs bf16 [N][4][D] = la|fa|da|fm ----
__global__ void __launch_bounds__(256) agg_kernel(
    const signed char* __restrict__ Xq, const signed char* __restrict__ Mq,
    const int* __restrict__ nbr, const int* __restrict__ tier,
    __hip_bfloat16* __restrict__ aggs)
{
    __shared__ int sPack[8 * KNBR];
    int tid = threadIdx.x;
    int blockCell = blockIdx.x * 8;
    if (tid < 8 * KNBR) {
        int g = blockCell * KNBR + tid;            // coalesced
        sPack[tid] = (nbr[g] << 2) | tier[g];
    }
    __syncthreads();

    int grp = tid >> 5, d = tid & 31;
    int c = blockCell + grp;
    int sAll = 0, s0 = 0, s1 = 0, sm = 0, n0 = 0, n1 = 0;
#pragma unroll
    for (int k = 0; k < KNBR; ++k) {
        int pk = sPack[grp * KNBR + k];            // uniform per 32-group
        int tt = pk & 3;
        int j  = pk >> 2;
        int q = Xq[j * D + d];                     // 32-B row gather
        bool t0 = (tt == 0), t1 = (tt == 1);
        sAll += q;
        s0 += t0 ? q : 0;   n0 += t0;
        s1 += t1 ? q : 0;   n1 += t1;
        if (t1) sm += Mq[j * D + d];               // group-uniform branch
    }
    int s2 = sAll - s0 - s1;
    float n2 = (float)(KNBR - n0 - n1);
    __hip_bfloat16* a = aggs + (size_t)c * 4 * D + d;
    a[0 * D] = __float2bfloat16((float)s0 * SXD / fmaxf((float)n0, 1.f));
    a[1 * D] = __float2bfloat16((float)s1 * SXD / fmaxf((float)n1, 1.f));
    a[2 * D] = __float2bfloat16((float)s2 * SXD / fmaxf(n2, 1.f));
    a[3 * D] = __float2bfloat16((float)sm * SMD / fmaxf((float)n1, 1.f));
}

// ---- kernel 3: fused experts + gate + combine; 64 cells/block, 4 role-waves ----
// role 0 = gate+combine, 1 = cnf, 2 = local, 3 = func.
// sX: cur f32 [64][32] XOR-swizzled (later: local result, then output).
// sA: aggs dwords [64][64] XOR-swizzled (later: func result f32 | cnf result f32).
__global__ void __launch_bounds__(256) moe_kernel(
    const float* __restrict__ X, const unsigned int* __restrict__ aggs,
    const float* __restrict__ Wl, const float* __restrict__ bl,
    const float* __restrict__ Wf, const float* __restrict__ bfv,
    const float* __restrict__ Wc, const float* __restrict__ bc,
    const float* __restrict__ Wg, const float* __restrict__ bg,
    float* __restrict__ out)
{
    __shared__ float sX[MC * 32];
    __shared__ unsigned int sA[MC * 64];
    int tid  = threadIdx.x;
    int base = blockIdx.x * MC;
    int cells = NCELL - base; if (cells > MC) cells = MC;

    // stage cur (coalesced float4 -> swizzled b32)
    const float4* gX = (const float4*)(X + (size_t)base * 32);
#pragma unroll
    for (int k = 0; k < 2; ++k) {
        int q4 = tid + k * 256;
        if (q4 * 4 < cells * 32) {
            float4 v = gX[q4];
            int g = q4 * 4, cc = g >> 5, j = g & 31, s = cc & 31;
            sX[cc * 32 + ((j + 0) ^ s)] = v.x;
            sX[cc * 32 + ((j + 1) ^ s)] = v.y;
            sX[cc * 32 + ((j + 2) ^ s)] = v.z;
            sX[cc * 32 + ((j + 3) ^ s)] = v.w;
        }
    }
    // stage aggs (coalesced uint4 -> swizzled dwords)
    const uint4* gA = (const uint4*)(aggs + (size_t)base * 64);
#pragma unroll
    for (int k = 0; k < 4; ++k) {
        int q4 = tid + k * 256;
        if (q4 * 4 < cells * 64) {
            uint4 v = gA[q4];
            int g = q4 * 4, cc = g >> 6, p = g & 63, s = cc & 31;
            sA[cc * 64 + ((p + 0) ^ s)] = v.x;
            sA[cc * 64 + ((p + 1) ^ s)] = v.y;
            sA[cc * 64 + ((p + 2) ^ s)] = v.z;
            sA[cc * 64 + ((p + 3) ^ s)] = v.w;
        }
    }
    __syncthreads();

    int role = tid >> 6, cc = tid & 63;
    int s = cc & 31;
    bool act = (cc < cells);
    float res[32];
    float w0 = 0.f, w1 = 0.f, w2 = 0.f;

    if (act && role == 0) {
        // ---- gate: softmax([cur;la;fa;da] @ Wg + bg) ----
        float g0 = bg[0], g1 = bg[1], g2 = bg[2];
#pragma unroll 8
        for (int j = 0; j < 32; ++j) {
            float v = sX[cc * 32 + (j ^ s)];
            g0 = fmaf(v, Wg[j*3+0], g0); g1 = fmaf(v, Wg[j*3+1], g1); g2 = fmaf(v, Wg[j*3+2], g2);
        }
#pragma unroll 8
        for (int p = 0; p < 48; ++p) {                 // la,fa,da dwords
            unsigned int dw = sA[cc * 64 + (p ^ s)];
            float vlo = bf2f(dw & 0xffffu), vhi = bf2f(dw >> 16);
            int r = 32 + p * 2;
            g0 = fmaf(vlo, Wg[r*3+0], g0); g1 = fmaf(vlo, Wg[r*3+1], g1); g2 = fmaf(vlo, Wg[r*3+2], g2);
            g0 = fmaf(vhi, Wg[(r+1)*3+0], g0); g1 = fmaf(vhi, Wg[(r+1)*3+1], g1); g2 = fmaf(vhi, Wg[(r+1)*3+2], g2);
        }
        float mx = fmaxf(g0, fmaxf(g1, g2));
        float e0 = __expf(g0 - mx), e1 = __expf(g1 - mx), e2 = __expf(g2 - mx);
        float inv = 1.f / (e0 + e1 + e2);
        w0 = e0 * inv; w1 = e1 * inv; w2 = e2 * inv;
    } else if (act && role == 1) {
        // ---- cnf: gc = bc + da @ Wc[32:64]; 3-step Euler ----
        float gc[32];
#pragma unroll
        for (int d0 = 0; d0 < 32; ++d0) gc[d0] = bc[d0];
#pragma unroll 4
        for (int p = 0; p < 16; ++p) {                 // da dwords 32..47
            unsigned int dw = sA[cc * 64 + ((32 + p) ^ s)];
            float vlo = bf2f(dw & 0xffffu), vhi = bf2f(dw >> 16);
            int j = 32 + p * 2;
#pragma unroll
            for (int d0 = 0; d0 < 32; ++d0) gc[d0] = fmaf(vlo, Wc[j * 32 + d0], gc[d0]);
#pragma unroll
            for (int d0 = 0; d0 < 32; ++d0) gc[d0] = fmaf(vhi, Wc[(j + 1) * 32 + d0], gc[d0]);
        }
        float xx[32];
#pragma unroll
        for (int d0 = 0; d0 < 32; ++d0) xx[d0] = sX[cc * 32 + (d0 ^ s)];
        const float dt = 1.0f / 3.0f;
#pragma unroll 1
        for (int st = 0; st < 3; ++st) {
            float a2[32];
#pragma unroll
            for (int d0 = 0; d0 < 32; ++d0) a2[d0] = gc[d0];
#pragma unroll 8
            for (int j = 0; j < 32; ++j) {
                float v = xx[j];
#pragma unroll
                for (int d0 = 0; d0 < 32; ++d0) a2[d0] = fmaf(v, Wc[j * 32 + d0], a2[d0]);
            }
#pragma unroll
            for (int d0 = 0; d0 < 32; ++d0) xx[d0] += dt * fast_tanh(a2[d0]);
        }
#pragma unroll
        for (int d0 = 0; d0 < 32; ++d0) res[d0] = xx[d0];
    } else if (act && role == 2) {
        // ---- local: tanh([cur ; la] @ Wl + bl) ----
#pragma unroll
        for (int d0 = 0; d0 < 32; ++d0) res[d0] = bl[d0];
#pragma unroll 8
        for (int j = 0; j < 32; ++j) {
            float v = sX[cc * 32 + (j ^ s)];
#pragma unroll
            for (int d0 = 0; d0 < 32; ++d0) res[d0] = fmaf(v, Wl[j * 32 + d0], res[d0]);
        }
#pragma unroll 4
        for (int p = 0; p < 16; ++p) {                 // la dwords 0..15
            unsigned int dw = sA[cc * 64 + (p ^ s)];
            float vlo = bf2f(dw & 0xffffu), vhi = bf2f(dw >> 16);
            int j = 32 + p * 2;
#pragma unroll
            for (int d0 = 0; d0 < 32; ++d0) res[d0] = fmaf(vlo, Wl[j * 32 + d0], res[d0]);
#pragma unroll
            for (int d0 = 0; d0 < 32; ++d0) res[d0] = fmaf(vhi, Wl[(j + 1) * 32 + d0], res[d0]);
        }
#pragma unroll
        for (int d0 = 0; d0 < 32; ++d0) res[d0] = fast_tanh(res[d0]);
    } else if (act && role == 3) {
        // ---- func: tanh([cur ; fm] @ Wf + bf) ----
#pragma unroll
        for (int d0 = 0; d0 < 32; ++d0) res[d0] = bfv[d0];
#pragma unroll 8
        for (int j = 0; j < 32; ++j) {
            float v = sX[cc * 32 + (j ^ s)];
#pragma unroll
            for (int d0 = 0; d0 < 32; ++d0) res[d0] = fmaf(v, Wf[j * 32 + d0], res[d0]);
        }
#pragma unroll 4
        for (int p = 0; p < 16; ++p) {                 // fm dwords 48..63
            unsigned int dw = sA[cc * 64 + ((48 + p) ^ s)];
            float vlo = bf2f(dw & 0xffffu), vhi = bf2f(dw >> 16);
            int j = 32 + p * 2;
#pragma unroll
            for (int d0 = 0; d0 < 32; ++d0) res[d0] = fmaf(vlo, Wf[j * 32 + d0], res[d0]);
#pragma unroll
            for (int d0 = 0; d0 < 32; ++d0) res[d0] = fmaf(vhi, Wf[(j + 1) * 32 + d0], res[d0]);
        }
#pragma unroll
        for (int d0 = 0; d0 < 32; ++d0) res[d0] = fast_tanh(res[d0]);
    }
    __syncthreads();   // all LDS input reads done

    float* sFr = (float*)sA;            // func result  [0 .. MC*32)
    float* sCr = sFr + MC * 32;         // cnf  result  [MC*32 .. MC*64)
    if (act) {
        if (role == 2) {
#pragma unroll
            for (int d0 = 0; d0 < 32; ++d0) sX[cc * 32 + (d0 ^ s)] = res[d0];
        } else if (role == 3) {
#pragma unroll
            for (int d0 = 0; d0 < 32; ++d0) sFr[cc * 32 + (d0 ^ s)] = res[d0];
        } else if (role == 1) {
#pragma unroll
            for (int d0 = 0; d0 < 32; ++d0) sCr[cc * 32 + (d0 ^ s)] = res[d0];
        }
    }
    __syncthreads();   // results visible

    if (act && role == 0) {
        float o[32];
#pragma unroll
        for (int d0 = 0; d0 < 32; ++d0) {
            float lo = sX [cc * 32 + (d0 ^ s)];
            float fo = sFr[cc * 32 + (d0 ^ s)];
            float xo = sCr[cc * 32 + (d0 ^ s)];
            o[d0] = w0 * lo + w1 * fo + w2 * xo;
        }
#pragma unroll
        for (int d0 = 0; d0 < 32; ++d0) sX[cc * 32 + (d0 ^ s)] = o[d0];
    }
    __syncthreads();   // output in sX

    // coalesced float4 store
    float4* gO = (float4*)(out + (size_t)base * 32);
#pragma unroll
    for (int k = 0; k < 2; ++k) {
        int q4 = tid + k * 256;
        if (q4 * 4 < cells * 32) {
            int g = q4 * 4, cc2 = g >> 5, j = g & 31, s2 = cc2 & 31;
            float4 v;
            v.x = sX[cc2 * 32 + ((j + 0) ^ s2)];
            v.y = sX[cc2 * 32 + ((j + 1) ^ s2)];
            v.z = sX[cc2 * 32 + ((j + 2) ^ s2)];
            v.w = sX[cc2 * 32 + ((j + 3) ^ s2)];
            gO[q4] = v;
        }
    }
}

extern "C" void kernel_launch(void* const* d_in, const int* in_sizes, int n_in,
                              void* d_out, int out_size, void* d_ws, size_t ws_size,
                              hipStream_t stream)
{
    const float* X    = (const float*)d_in[0];
    const int*   nbr  = (const int*)  d_in[1];
    const int*   tier = (const int*)  d_in[2];
    const float* Wl   = (const float*)d_in[3];
    const float* bl   = (const float*)d_in[4];
    const float* Wm   = (const float*)d_in[5];
    const float* bm   = (const float*)d_in[6];
    const float* Wf   = (const float*)d_in[7];
    const float* bf   = (const float*)d_in[8];
    const float* Wc   = (const float*)d_in[9];
    const float* bc   = (const float*)d_in[10];
    const float* Wg   = (const float*)d_in[11];
    const float* bg   = (const float*)d_in[12];
    float* out = (float*)d_out;

    const size_t ND = (size_t)NCELL * D;
    signed char* Xq = (signed char*)d_ws;          // 4 MB
    signed char* Mq = Xq + ND;                     // 4 MB
    __hip_bfloat16* aggs = (__hip_bfloat16*)(Mq + ND);   // N*4*D bf16 = 32 MB

    dim3 blk(256);
    msg_kernel<<<dim3(ND / 256), blk, 0, stream>>>(X, Wm, bm, Xq, Mq);
    agg_kernel<<<dim3(NCELL / 8), blk, 0, stream>>>(Xq, Mq, nbr, tier, aggs);
    moe_kernel<<<dim3((NCELL + MC - 1) / MC), blk, 0, stream>>>(
        X, (const unsigned int*)aggs, Wl, bl, Wf, bf, Wc, bc, Wg, bg, out);
}

// Round 8
// 226.548 us; speedup vs baseline: 1.1047x; 1.1047x over previous
//
#include <hip/hip_runtime.h>
#include <hip/hip_bf16.h>
#include <math.h>

#define NCELL 125000
#define KNBR  26
#define D     32
#define MC    64            // cells per moe block

#define SXE (127.0f/7.0f)   // X encode scale (clamp +-7)
#define SXD (7.0f/127.0f)   // X decode
#define SMD (1.0f/127.0f)   // M decode (tanh in [-1,1])

typedef unsigned int uint4v __attribute__((ext_vector_type(4)));
typedef float float4v __attribute__((ext_vector_type(4)));

__device__ __forceinline__ float fast_tanh(float x) {
    float e = __expf(2.0f * x);
    return 1.0f - 2.0f / (e + 1.0f);
}
__device__ __forceinline__ float bf2f(unsigned int h) {
    return __uint_as_float(h << 16);
}
__device__ __forceinline__ unsigned short f2bf(float f) {   // RNE
    unsigned int u = __float_as_uint(f);
    u += 0x7fffu + ((u >> 16) & 1u);
    return (unsigned short)(u >> 16);
}

// ---- kernel 1: XM[c][d] = (int8(tanh(X@Wm+bm)) << 8) | int8(X) ----
// thread = (c,d); N*D = 4,000,000 = 256 * 15625 exactly
__global__ void __launch_bounds__(256) msg_kernel(
    const float* __restrict__ X, const float* __restrict__ Wm,
    const float* __restrict__ bm, unsigned short* __restrict__ XM)
{
    __shared__ float sX[256];
    int t = blockIdx.x * 256 + threadIdx.x;
    float v = X[t];
    sX[threadIdx.x] = v;
    __syncthreads();
    int d = t & 31;
    int base = threadIdx.x & ~31;
    float acc = bm[d];
#pragma unroll
    for (int j = 0; j < D; ++j)
        acc = fmaf(sX[base + j], Wm[j * D + d], acc);
    int xq = __float2int_rn(fminf(fmaxf(v, -7.f), 7.f) * SXE);
    int mq = __float2int_rn(fast_tanh(acc) * 127.0f);
    XM[t] = (unsigned short)(((mq & 0xff) << 8) | (xq & 0xff));
}

// ---- kernel 2: one-line-per-neighbor gather -> aggs bf16 [N][4][D] ----
__global__ void __launch_bounds__(256) agg_kernel(
    const unsigned short* __restrict__ XM,
    const int* __restrict__ nbr, const int* __restrict__ tier,
    unsigned short* __restrict__ aggs)   // bf16 bits
{
    __shared__ int sPack[8 * KNBR];
    int tid = threadIdx.x;
    int blockCell = blockIdx.x * 8;
    if (tid < 8 * KNBR) {
        int g = blockCell * KNBR + tid;                   // coalesced, streaming
        int jj = __builtin_nontemporal_load(&nbr[g]);
        int tt = __builtin_nontemporal_load(&tier[g]);
        sPack[tid] = (jj << 2) | tt;
    }
    __syncthreads();

    int grp = tid >> 5, d = tid & 31;
    int c = blockCell + grp;
    int sAll = 0, s0 = 0, s1 = 0, sm = 0, n0 = 0, n1 = 0;
#pragma unroll
    for (int k = 0; k < KNBR; ++k) {
        int pk = sPack[grp * KNBR + k];                   // uniform per 32-group
        int tt = pk & 3;
        int j  = pk >> 2;
        unsigned short v = XM[j * D + d];                 // ONE 64-B line per row
        int x = (int)(signed char)(v & 0xff);
        int m = (int)(signed char)(v >> 8);
        bool t0 = (tt == 0), t1 = (tt == 1);
        sAll += x;
        s0 += t0 ? x : 0;   n0 += t0;
        s1 += t1 ? x : 0;   n1 += t1;
        sm += t1 ? m : 0;
    }
    int s2 = sAll - s0 - s1;
    float n2 = (float)(KNBR - n0 - n1);
    unsigned short* a = aggs + (size_t)c * 4 * D + d;
    __builtin_nontemporal_store(f2bf((float)s0 * SXD / fmaxf((float)n0, 1.f)), a + 0 * D);
    __builtin_nontemporal_store(f2bf((float)s1 * SXD / fmaxf((float)n1, 1.f)), a + 1 * D);
    __builtin_nontemporal_store(f2bf((float)s2 * SXD / fmaxf(n2, 1.f)),        a + 2 * D);
    __builtin_nontemporal_store(f2bf((float)sm * SMD / fmaxf((float)n1, 1.f)), a + 3 * D);
}

// ---- kernel 3: fused experts + gate + combine; 64 cells/block, 4 role-waves ----
// role 0 = gate+combine, 1 = cnf, 2 = local, 3 = func.
__global__ void __launch_bounds__(256) moe_kernel(
    const float* __restrict__ X, const unsigned int* __restrict__ aggs,
    const float* __restrict__ Wl, const float* __restrict__ bl,
    const float* __restrict__ Wf, const float* __restrict__ bfv,
    const float* __restrict__ Wc, const float* __restrict__ bc,
    const float* __restrict__ Wg, const float* __restrict__ bg,
    float* __restrict__ out)
{
    __shared__ float sX[MC * 32];
    __shared__ unsigned int sA[MC * 64];
    int tid  = threadIdx.x;
    int base = blockIdx.x * MC;
    int cells = NCELL - base; if (cells > MC) cells = MC;

    // stage cur (coalesced float4 -> swizzled b32)
    const float4* gX = (const float4*)(X + (size_t)base * 32);
#pragma unroll
    for (int k = 0; k < 2; ++k) {
        int q4 = tid + k * 256;
        if (q4 * 4 < cells * 32) {
            float4 v = gX[q4];
            int g = q4 * 4, cc = g >> 5, j = g & 31, s = cc & 31;
            sX[cc * 32 + ((j + 0) ^ s)] = v.x;
            sX[cc * 32 + ((j + 1) ^ s)] = v.y;
            sX[cc * 32 + ((j + 2) ^ s)] = v.z;
            sX[cc * 32 + ((j + 3) ^ s)] = v.w;
        }
    }
    // stage aggs (coalesced NT uint4 -> swizzled dwords)
    const uint4v* gA = (const uint4v*)(aggs + (size_t)base * 64);
#pragma unroll
    for (int k = 0; k < 4; ++k) {
        int q4 = tid + k * 256;
        if (q4 * 4 < cells * 64) {
            uint4v v = __builtin_nontemporal_load(&gA[q4]);
            int g = q4 * 4, cc = g >> 6, p = g & 63, s = cc & 31;
            sA[cc * 64 + ((p + 0) ^ s)] = v.x;
            sA[cc * 64 + ((p + 1) ^ s)] = v.y;
            sA[cc * 64 + ((p + 2) ^ s)] = v.z;
            sA[cc * 64 + ((p + 3) ^ s)] = v.w;
        }
    }
    __syncthreads();

    int role = tid >> 6, cc = tid & 63;
    int s = cc & 31;
    bool act = (cc < cells);
    float res[32];
    float w0 = 0.f, w1 = 0.f, w2 = 0.f;

    if (act && role == 0) {
        // ---- gate ----
        float g0 = bg[0], g1 = bg[1], g2 = bg[2];
#pragma unroll 8
        for (int j = 0; j < 32; ++j) {
            float v = sX[cc * 32 + (j ^ s)];
            g0 = fmaf(v, Wg[j*3+0], g0); g1 = fmaf(v, Wg[j*3+1], g1); g2 = fmaf(v, Wg[j*3+2], g2);
        }
#pragma unroll 8
        for (int p = 0; p < 48; ++p) {                 // la,fa,da dwords
            unsigned int dw = sA[cc * 64 + (p ^ s)];
            float vlo = bf2f(dw & 0xffffu), vhi = bf2f(dw >> 16);
            int r = 32 + p * 2;
            g0 = fmaf(vlo, Wg[r*3+0], g0); g1 = fmaf(vlo, Wg[r*3+1], g1); g2 = fmaf(vlo, Wg[r*3+2], g2);
            g0 = fmaf(vhi, Wg[(r+1)*3+0], g0); g1 = fmaf(vhi, Wg[(r+1)*3+1], g1); g2 = fmaf(vhi, Wg[(r+1)*3+2], g2);
        }
        float mx = fmaxf(g0, fmaxf(g1, g2));
        float e0 = __expf(g0 - mx), e1 = __expf(g1 - mx), e2 = __expf(g2 - mx);
        float inv = 1.f / (e0 + e1 + e2);
        w0 = e0 * inv; w1 = e1 * inv; w2 = e2 * inv;
    } else if (act && role == 1) {
        // ---- cnf: res doubles as a2; xx evolves in place ----
        float gc[32], xx[32];
#pragma unroll
        for (int d0 = 0; d0 < 32; ++d0) gc[d0] = bc[d0];
#pragma unroll 4
        for (int p = 0; p < 16; ++p) {                 // da dwords 32..47
            unsigned int dw = sA[cc * 64 + ((32 + p) ^ s)];
            float vlo = bf2f(dw & 0xffffu), vhi = bf2f(dw >> 16);
            int j = 32 + p * 2;
#pragma unroll
            for (int d0 = 0; d0 < 32; ++d0) gc[d0] = fmaf(vlo, Wc[j * 32 + d0], gc[d0]);
#pragma unroll
            for (int d0 = 0; d0 < 32; ++d0) gc[d0] = fmaf(vhi, Wc[(j + 1) * 32 + d0], gc[d0]);
        }
#pragma unroll
        for (int d0 = 0; d0 < 32; ++d0) xx[d0] = sX[cc * 32 + (d0 ^ s)];
        const float dt = 1.0f / 3.0f;
#pragma unroll 1
        for (int st = 0; st < 3; ++st) {
#pragma unroll
            for (int d0 = 0; d0 < 32; ++d0) res[d0] = gc[d0];
#pragma unroll 8
            for (int j = 0; j < 32; ++j) {
                float v = xx[j];
#pragma unroll
                for (int d0 = 0; d0 < 32; ++d0) res[d0] = fmaf(v, Wc[j * 32 + d0], res[d0]);
            }
#pragma unroll
            for (int d0 = 0; d0 < 32; ++d0) xx[d0] += dt * fast_tanh(res[d0]);
        }
#pragma unroll
        for (int d0 = 0; d0 < 32; ++d0) res[d0] = xx[d0];
    } else if (act && role == 2) {
        // ---- local ----
#pragma unroll
        for (int d0 = 0; d0 < 32; ++d0) res[d0] = bl[d0];
#pragma unroll 8
        for (int j = 0; j < 32; ++j) {
            float v = sX[cc * 32 + (j ^ s)];
#pragma unroll
            for (int d0 = 0; d0 < 32; ++d0) res[d0] = fmaf(v, Wl[j * 32 + d0], res[d0]);
        }
#pragma unroll 4
        for (int p = 0; p < 16; ++p) {                 // la dwords 0..15
            unsigned int dw = sA[cc * 64 + (p ^ s)];
            float vlo = bf2f(dw & 0xffffu), vhi = bf2f(dw >> 16);
            int j = 32 + p * 2;
#pragma unroll
            for (int d0 = 0; d0 < 32; ++d0) res[d0] = fmaf(vlo, Wl[j * 32 + d0], res[d0]);
#pragma unroll
            for (int d0 = 0; d0 < 32; ++d0) res[d0] = fmaf(vhi, Wl[(j + 1) * 32 + d0], res[d0]);
        }
#pragma unroll
        for (int d0 = 0; d0 < 32; ++d0) res[d0] = fast_tanh(res[d0]);
    } else if (act && role == 3) {
        // ---- func ----
#pragma unroll
        for (int d0 = 0; d0 < 32; ++d0) res[d0] = bfv[d0];
#pragma unroll 8
        for (int j = 0; j < 32; ++j) {
            float v = sX[cc * 32 + (j ^ s)];
#pragma unroll
            for (int d0 = 0; d0 < 32; ++d0) res[d0] = fmaf(v, Wf[j * 32 + d0], res[d0]);
        }
#pragma unroll 4
        for (int p = 0; p < 16; ++p) {                 // fm dwords 48..63
            unsigned int dw = sA[cc * 64 + ((48 + p) ^ s)];
            float vlo = bf2f(dw & 0xffffu), vhi = bf2f(dw >> 16);
            int j = 32 + p * 2;
#pragma unroll
            for (int d0 = 0; d0 < 32; ++d0) res[d0] = fmaf(vlo, Wf[j * 32 + d0], res[d0]);
#pragma unroll
            for (int d0 = 0; d0 < 32; ++d0) res[d0] = fmaf(vhi, Wf[(j + 1) * 32 + d0], res[d0]);
        }
#pragma unroll
        for (int d0 = 0; d0 < 32; ++d0) res[d0] = fast_tanh(res[d0]);
    }
    __syncthreads();   // all LDS input reads done

    float* sFr = (float*)sA;            // func result  [0 .. MC*32)
    float* sCr = sFr + MC * 32;         // cnf  result  [MC*32 .. MC*64)
    if (act) {
        if (role == 2) {
#pragma unroll
            for (int d0 = 0; d0 < 32; ++d0) sX[cc * 32 + (d0 ^ s)] = res[d0];
        } else if (role == 3) {
#pragma unroll
            for (int d0 = 0; d0 < 32; ++d0) sFr[cc * 32 + (d0 ^ s)] = res[d0];
        } else if (role == 1) {
#pragma unroll
            for (int d0 = 0; d0 < 32; ++d0) sCr[cc * 32 + (d0 ^ s)] = res[d0];
        }
    }
    __syncthreads();   // results visible

    if (act && role == 0) {
        float o[32];
#pragma unroll
        for (int d0 = 0; d0 < 32; ++d0) {
            float lo = sX [cc * 32 + (d0 ^ s)];
            float fo = sFr[cc * 32 + (d0 ^ s)];
            float xo = sCr[cc * 32 + (d0 ^ s)];
            o[d0] = w0 * lo + w1 * fo + w2 * xo;
        }
#pragma unroll
        for (int d0 = 0; d0 < 32; ++d0) sX[cc * 32 + (d0 ^ s)] = o[d0];
    }
    __syncthreads();   // output in sX

    // coalesced NT float4 store
    float4v* gO = (float4v*)(out + (size_t)base * 32);
#pragma unroll
    for (int k = 0; k < 2; ++k) {
        int q4 = tid + k * 256;
        if (q4 * 4 < cells * 32) {
            int g = q4 * 4, cc2 = g >> 5, j = g & 31, s2 = cc2 & 31;
            float4v v;
            v.x = sX[cc2 * 32 + ((j + 0) ^ s2)];
            v.y = sX[cc2 * 32 + ((j + 1) ^ s2)];
            v.z = sX[cc2 * 32 + ((j + 2) ^ s2)];
            v.w = sX[cc2 * 32 + ((j + 3) ^ s2)];
            __builtin_nontemporal_store(v, &gO[q4]);
        }
    }
}

extern "C" void kernel_launch(void* const* d_in, const int* in_sizes, int n_in,
                              void* d_out, int out_size, void* d_ws, size_t ws_size,
                              hipStream_t stream)
{
    const float* X    = (const float*)d_in[0];
    const int*   nbr  = (const int*)  d_in[1];
    const int*   tier = (const int*)  d_in[2];
    const float* Wl   = (const float*)d_in[3];
    const float* bl   = (const float*)d_in[4];
    const float* Wm   = (const float*)d_in[5];
    const float* bm   = (const float*)d_in[6];
    const float* Wf   = (const float*)d_in[7];
    const float* bf   = (const float*)d_in[8];
    const float* Wc   = (const float*)d_in[9];
    const float* bc   = (const float*)d_in[10];
    const float* Wg   = (const float*)d_in[11];
    const float* bg   = (const float*)d_in[12];
    float* out = (float*)d_out;

    const size_t ND = (size_t)NCELL * D;
    unsigned short* XM = (unsigned short*)d_ws;           // 8 MB interleaved x|m
    unsigned short* aggs = XM + ND;                       // N*4*D bf16 = 32 MB

    dim3 blk(256);
    msg_kernel<<<dim3(ND / 256), blk, 0, stream>>>(X, Wm, bm, XM);
    agg_kernel<<<dim3(NCELL / 8), blk, 0, stream>>>(XM, nbr, tier, aggs);
    moe_kernel<<<dim3((NCELL + MC - 1) / MC), blk, 0, stream>>>(
        X, (const unsigned int*)aggs, Wl, bl, Wf, bf, Wc, bc, Wg, bg, out);
}

// Round 9
// 222.602 us; speedup vs baseline: 1.1243x; 1.0177x over previous
//
#include <hip/hip_runtime.h>
#include <hip/hip_bf16.h>
#include <math.h>

#define NCELL 125000
#define KNBR  26
#define D     32
#define MC    64            // cells per fused block

#define SXE (127.0f/7.0f)   // X encode scale (clamp +-7)
#define SXD (7.0f/127.0f)   // X decode
#define SMD (1.0f/127.0f)   // M decode (tanh in [-1,1])

typedef float float4v __attribute__((ext_vector_type(4)));

__device__ __forceinline__ float fast_tanh(float x) {
    float e = __expf(2.0f * x);
    return 1.0f - 2.0f / (e + 1.0f);
}
__device__ __forceinline__ float bf2f(unsigned int h) {
    return __uint_as_float(h << 16);
}
__device__ __forceinline__ unsigned short f2bf(float f) {   // RNE
    unsigned int u = __float_as_uint(f);
    u += 0x7fffu + ((u >> 16) & 1u);
    return (unsigned short)(u >> 16);
}

// ---- kernel 1: XM[c][d] = (int8(tanh(X@Wm+bm)) << 8) | int8(X) ----
// thread = (c,d); N*D = 4,000,000 = 256 * 15625 exactly
__global__ void __launch_bounds__(256) msg_kernel(
    const float* __restrict__ X, const float* __restrict__ Wm,
    const float* __restrict__ bm, unsigned short* __restrict__ XM)
{
    __shared__ float sX[256];
    int t = blockIdx.x * 256 + threadIdx.x;
    float v = X[t];
    sX[threadIdx.x] = v;
    __syncthreads();
    int d = t & 31;
    int base = threadIdx.x & ~31;
    float acc = bm[d];
#pragma unroll
    for (int j = 0; j < D; ++j)
        acc = fmaf(sX[base + j], Wm[j * D + d], acc);
    int xq = __float2int_rn(fminf(fmaxf(v, -7.f), 7.f) * SXE);
    int mq = __float2int_rn(fast_tanh(acc) * 127.0f);
    XM[t] = (unsigned short)(((mq & 0xff) << 8) | (xq & 0xff));
}

// ---- kernel 2: FUSED gather + tier means (LDS only) + experts + gate + combine ----
// 64 cells/block, 256 threads. Phase A: 8 groups gather 8 cell-slots each,
// write bf16 aggs to swizzled LDS. Phase B: role waves (gate/cnf/local/func).
__global__ void __launch_bounds__(256) fused_kernel(
    const float* __restrict__ X, const unsigned short* __restrict__ XM,
    const int* __restrict__ nbr, const int* __restrict__ tier,
    const float* __restrict__ Wl, const float* __restrict__ bl,
    const float* __restrict__ Wf, const float* __restrict__ bfv,
    const float* __restrict__ Wc, const float* __restrict__ bc,
    const float* __restrict__ Wg, const float* __restrict__ bg,
    float* __restrict__ out)
{
    __shared__ float sX[MC * 32];
    __shared__ unsigned int sA[MC * 64];     // bf16 pairs [la|fa|da|fm], swizzled
    __shared__ int sPack[MC * KNBR];
    unsigned short* sA16 = (unsigned short*)sA;

    int tid  = threadIdx.x;
    int base = blockIdx.x * MC;
    int cells = NCELL - base; if (cells > MC) cells = MC;

    // stage neighbor pack (coalesced, streaming)
    for (int i = tid; i < cells * KNBR; i += 256) {
        int jj = __builtin_nontemporal_load(&nbr[base * KNBR + i]);
        int tt = __builtin_nontemporal_load(&tier[base * KNBR + i]);
        sPack[i] = (jj << 2) | tt;
    }
    // stage cur (coalesced float4 -> swizzled b32)
    const float4* gX = (const float4*)(X + (size_t)base * 32);
#pragma unroll
    for (int k = 0; k < 2; ++k) {
        int q4 = tid + k * 256;
        if (q4 * 4 < cells * 32) {
            float4 v = gX[q4];
            int g = q4 * 4, cc = g >> 5, j = g & 31, s = cc & 31;
            sX[cc * 32 + ((j + 0) ^ s)] = v.x;
            sX[cc * 32 + ((j + 1) ^ s)] = v.y;
            sX[cc * 32 + ((j + 2) ^ s)] = v.z;
            sX[cc * 32 + ((j + 3) ^ s)] = v.w;
        }
    }
    __syncthreads();

    // ---- Phase A: gather + tier means, straight into LDS ----
    int grp = tid >> 5, d = tid & 31;
#pragma unroll 1
    for (int slot = grp; slot < MC; slot += 8) {
        if (slot < cells) {
            int sAll = 0, s0 = 0, s1 = 0, sm = 0, n0 = 0, n1 = 0;
#pragma unroll
            for (int k = 0; k < KNBR; ++k) {
                int pk = sPack[slot * KNBR + k];          // uniform per group
                int tt = pk & 3;
                int j  = pk >> 2;
                unsigned short v = XM[j * D + d];         // ONE 64-B line per row
                int x = (int)(signed char)(v & 0xff);
                int m = (int)(signed char)(v >> 8);
                bool t0 = (tt == 0), t1 = (tt == 1);
                sAll += x;
                s0 += t0 ? x : 0;   n0 += t0;
                s1 += t1 ? x : 0;   n1 += t1;
                sm += t1 ? m : 0;
            }
            int s2 = sAll - s0 - s1;
            float n2 = (float)(KNBR - n0 - n1);
            int s = slot & 31;
            int b16 = slot * 128;
            int p = d >> 1, h = d & 1;
            sA16[b16 + ((( 0 + p) ^ s) << 1) + h] = f2bf((float)s0 * SXD / fmaxf((float)n0, 1.f));
            sA16[b16 + (((16 + p) ^ s) << 1) + h] = f2bf((float)s1 * SXD / fmaxf((float)n1, 1.f));
            sA16[b16 + (((32 + p) ^ s) << 1) + h] = f2bf((float)s2 * SXD / fmaxf(n2, 1.f));
            sA16[b16 + (((48 + p) ^ s) << 1) + h] = f2bf((float)sm * SMD / fmaxf((float)n1, 1.f));
        }
    }
    __syncthreads();

    // ---- Phase B: role waves ----
    int role = tid >> 6, cc = tid & 63;
    int s = cc & 31;
    bool act = (cc < cells);
    float res[32];
    float w0 = 0.f, w1 = 0.f, w2 = 0.f;

    if (act && role == 0) {
        // ---- gate ----
        float g0 = bg[0], g1 = bg[1], g2 = bg[2];
#pragma unroll 8
        for (int j = 0; j < 32; ++j) {
            float v = sX[cc * 32 + (j ^ s)];
            g0 = fmaf(v, Wg[j*3+0], g0); g1 = fmaf(v, Wg[j*3+1], g1); g2 = fmaf(v, Wg[j*3+2], g2);
        }
#pragma unroll 8
        for (int p = 0; p < 48; ++p) {                 // la,fa,da dwords
            unsigned int dw = sA[cc * 64 + (p ^ s)];
            float vlo = bf2f(dw & 0xffffu), vhi = bf2f(dw >> 16);
            int r = 32 + p * 2;
            g0 = fmaf(vlo, Wg[r*3+0], g0); g1 = fmaf(vlo, Wg[r*3+1], g1); g2 = fmaf(vlo, Wg[r*3+2], g2);
            g0 = fmaf(vhi, Wg[(r+1)*3+0], g0); g1 = fmaf(vhi, Wg[(r+1)*3+1], g1); g2 = fmaf(vhi, Wg[(r+1)*3+2], g2);
        }
        float mx = fmaxf(g0, fmaxf(g1, g2));
        float e0 = __expf(g0 - mx), e1 = __expf(g1 - mx), e2 = __expf(g2 - mx);
        float inv = 1.f / (e0 + e1 + e2);
        w0 = e0 * inv; w1 = e1 * inv; w2 = e2 * inv;
    } else if (act && role == 1) {
        // ---- cnf ----
        float gc[32], xx[32];
#pragma unroll
        for (int d0 = 0; d0 < 32; ++d0) gc[d0] = bc[d0];
#pragma unroll 4
        for (int p = 0; p < 16; ++p) {                 // da dwords 32..47
            unsigned int dw = sA[cc * 64 + ((32 + p) ^ s)];
            float vlo = bf2f(dw & 0xffffu), vhi = bf2f(dw >> 16);
            int j = 32 + p * 2;
#pragma unroll
            for (int d0 = 0; d0 < 32; ++d0) gc[d0] = fmaf(vlo, Wc[j * 32 + d0], gc[d0]);
#pragma unroll
            for (int d0 = 0; d0 < 32; ++d0) gc[d0] = fmaf(vhi, Wc[(j + 1) * 32 + d0], gc[d0]);
        }
#pragma unroll
        for (int d0 = 0; d0 < 32; ++d0) xx[d0] = sX[cc * 32 + (d0 ^ s)];
        const float dt = 1.0f / 3.0f;
#pragma unroll 1
        for (int st = 0; st < 3; ++st) {
#pragma unroll
            for (int d0 = 0; d0 < 32; ++d0) res[d0] = gc[d0];
#pragma unroll 8
            for (int j = 0; j < 32; ++j) {
                float v = xx[j];
#pragma unroll
                for (int d0 = 0; d0 < 32; ++d0) res[d0] = fmaf(v, Wc[j * 32 + d0], res[d0]);
            }
#pragma unroll
            for (int d0 = 0; d0 < 32; ++d0) xx[d0] += dt * fast_tanh(res[d0]);
        }
#pragma unroll
        for (int d0 = 0; d0 < 32; ++d0) res[d0] = xx[d0];
    } else if (act && role == 2) {
        // ---- local ----
#pragma unroll
        for (int d0 = 0; d0 < 32; ++d0) res[d0] = bl[d0];
#pragma unroll 8
        for (int j = 0; j < 32; ++j) {
            float v = sX[cc * 32 + (j ^ s)];
#pragma unroll
            for (int d0 = 0; d0 < 32; ++d0) res[d0] = fmaf(v, Wl[j * 32 + d0], res[d0]);
        }
#pragma unroll 4
        for (int p = 0; p < 16; ++p) {                 // la dwords 0..15
            unsigned int dw = sA[cc * 64 + (p ^ s)];
            float vlo = bf2f(dw & 0xffffu), vhi = bf2f(dw >> 16);
            int j = 32 + p * 2;
#pragma unroll
            for (int d0 = 0; d0 < 32; ++d0) res[d0] = fmaf(vlo, Wl[j * 32 + d0], res[d0]);
#pragma unroll
            for (int d0 = 0; d0 < 32; ++d0) res[d0] = fmaf(vhi, Wl[(j + 1) * 32 + d0], res[d0]);
        }
#pragma unroll
        for (int d0 = 0; d0 < 32; ++d0) res[d0] = fast_tanh(res[d0]);
    } else if (act && role == 3) {
        // ---- func ----
#pragma unroll
        for (int d0 = 0; d0 < 32; ++d0) res[d0] = bfv[d0];
#pragma unroll 8
        for (int j = 0; j < 32; ++j) {
            float v = sX[cc * 32 + (j ^ s)];
#pragma unroll
            for (int d0 = 0; d0 < 32; ++d0) res[d0] = fmaf(v, Wf[j * 32 + d0], res[d0]);
        }
#pragma unroll 4
        for (int p = 0; p < 16; ++p) {                 // fm dwords 48..63
            unsigned int dw = sA[cc * 64 + ((48 + p) ^ s)];
            float vlo = bf2f(dw & 0xffffu), vhi = bf2f(dw >> 16);
            int j = 32 + p * 2;
#pragma unroll
            for (int d0 = 0; d0 < 32; ++d0) res[d0] = fmaf(vlo, Wf[j * 32 + d0], res[d0]);
#pragma unroll
            for (int d0 = 0; d0 < 32; ++d0) res[d0] = fmaf(vhi, Wf[(j + 1) * 32 + d0], res[d0]);
        }
#pragma unroll
        for (int d0 = 0; d0 < 32; ++d0) res[d0] = fast_tanh(res[d0]);
    }
    __syncthreads();   // all LDS input reads done

    float* sFr = (float*)sA;            // func result  [0 .. MC*32)
    float* sCr = sFr + MC * 32;         // cnf  result  [MC*32 .. MC*64)
    if (act) {
        if (role == 2) {
#pragma unroll
            for (int d0 = 0; d0 < 32; ++d0) sX[cc * 32 + (d0 ^ s)] = res[d0];
        } else if (role == 3) {
#pragma unroll
            for (int d0 = 0; d0 < 32; ++d0) sFr[cc * 32 + (d0 ^ s)] = res[d0];
        } else if (role == 1) {
#pragma unroll
            for (int d0 = 0; d0 < 32; ++d0) sCr[cc * 32 + (d0 ^ s)] = res[d0];
        }
    }
    __syncthreads();   // results visible

    if (act && role == 0) {
        float o[32];
#pragma unroll
        for (int d0 = 0; d0 < 32; ++d0) {
            float lo = sX [cc * 32 + (d0 ^ s)];
            float fo = sFr[cc * 32 + (d0 ^ s)];
            float xo = sCr[cc * 32 + (d0 ^ s)];
            o[d0] = w0 * lo + w1 * fo + w2 * xo;
        }
#pragma unroll
        for (int d0 = 0; d0 < 32; ++d0) sX[cc * 32 + (d0 ^ s)] = o[d0];
    }
    __syncthreads();   // output in sX

    // coalesced NT float4 store
    float4v* gO = (float4v*)(out + (size_t)base * 32);
#pragma unroll
    for (int k = 0; k < 2; ++k) {
        int q4 = tid + k * 256;
        if (q4 * 4 < cells * 32) {
            int g = q4 * 4, cc2 = g >> 5, j = g & 31, s2 = cc2 & 31;
            float4v v;
            v.x = sX[cc2 * 32 + ((j + 0) ^ s2)];
            v.y = sX[cc2 * 32 + ((j + 1) ^ s2)];
            v.z = sX[cc2 * 32 + ((j + 2) ^ s2)];
            v.w = sX[cc2 * 32 + ((j + 3) ^ s2)];
            __builtin_nontemporal_store(v, &gO[q4]);
        }
    }
}

extern "C" void kernel_launch(void* const* d_in, const int* in_sizes, int n_in,
                              void* d_out, int out_size, void* d_ws, size_t ws_size,
                              hipStream_t stream)
{
    const float* X    = (const float*)d_in[0];
    const int*   nbr  = (const int*)  d_in[1];
    const int*   tier = (const int*)  d_in[2];
    const float* Wl   = (const float*)d_in[3];
    const float* bl   = (const float*)d_in[4];
    const float* Wm   = (const float*)d_in[5];
    const float* bm   = (const float*)d_in[6];
    const float* Wf   = (const float*)d_in[7];
    const float* bf   = (const float*)d_in[8];
    const float* Wc   = (const float*)d_in[9];
    const float* bc   = (const float*)d_in[10];
    const float* Wg   = (const float*)d_in[11];
    const float* bg   = (const float*)d_in[12];
    float* out = (float*)d_out;

    const size_t ND = (size_t)NCELL * D;
    unsigned short* XM = (unsigned short*)d_ws;           // 8 MB interleaved x|m

    dim3 blk(256);
    msg_kernel<<<dim3(ND / 256), blk, 0, stream>>>(X, Wm, bm, XM);
    fused_kernel<<<dim3((NCELL + MC - 1) / MC), blk, 0, stream>>>(
        X, XM, nbr, tier, Wl, bl, Wf, bf, Wc, bc, Wg, bg, out);
}